// Round 1
// 133.026 us; speedup vs baseline: 1.0256x; 1.0256x over previous
//
#include <hip/hip_runtime.h>
#include <math.h>

#define EDIM 100
#define KP   128          // padded K
#define NF   4000
#define NN   4000
#define NB   8
#define NP   4096         // padded N and F
#define BN   128          // n-rows per block
#define BF   64           // f-cols per block
#define NFB  (NP / BF)    // 64 f-blocks
#define FPB  4            // f-blocks folded per main block
#define NYB  (NFB / FPB)  // 16 = gridDim.y of main
#define TRS  68           // transpose row stride (floats): 64 + 4 pad, 16B-aligned

#define CONVB (3 * (NP * KP / 256))   // 6144 convert blocks
#define PREPB ((NP / 64) * NB)        // 512 precompute_P blocks
#define E2B   ((NN + 255) / 256)      // 16 e2 blocks

typedef __attribute__((ext_vector_type(8))) short short8;
typedef __attribute__((ext_vector_type(4))) float floatx4;

// Static device scratch.
__device__ __align__(16) unsigned short g_A [NP * KP];   // ent  bf16, K-padded
__device__ __align__(16) unsigned short g_B1[NP * KP];   // fa1  bf16
__device__ __align__(16) unsigned short g_B2[NP * KP];   // fa2  bf16
__device__ __align__(16) float g_P[2 * NB * NP];         // [g][b][f], +INF on f-pad
__device__ float g_e2[NN];
__device__ float g_part[2 * NB * NYB * NP];              // [g][b][yblk][n]  (4 MB)

__device__ __forceinline__ unsigned short f2bf(float x) {
    union { float f; unsigned int u; } v; v.f = x;
    unsigned int r = v.u + 0x7FFFu + ((v.u >> 16) & 1u);  // RNE
    return (unsigned short)(r >> 16);
}

// ---- merged prep: convert (6144 blk) | precompute_P (512 blk) | e2 (16 blk) ----
__global__ void prep(const float* __restrict__ rel,  const float* __restrict__ arg1,
                     const float* __restrict__ arg2, const float* __restrict__ frel,
                     const float* __restrict__ fa1,  const float* __restrict__ fa2,
                     const float* __restrict__ ent) {
    const int bx = blockIdx.x;
    const int t  = threadIdx.x;

    if (bx < CONVB) {
        // fp32 [4000][100] -> bf16 [4096][128] zero-padded
        int plane = bx / (NP * KP / 256);
        int idx = (bx - plane * (NP * KP / 256)) * 256 + t;
        const float* src = (plane == 0) ? ent : (plane == 1) ? fa1 : fa2;
        unsigned short* dst = (plane == 0) ? g_A : (plane == 1) ? g_B1 : g_B2;
        int row = idx >> 7, k = idx & (KP - 1);
        float v = (row < NF && k < EDIM) ? src[row * EDIM + k] : 0.f;
        dst[idx] = f2bf(v);
    } else if (bx < CONVB + PREPB) {
        // P[g][b][f]; one wave per 16 f's, lanes = (f_local 16) x (k-quarter 4)
        int pb = bx - CONVB;
        int b   = pb >> 6;            // 0..7
        int fbx = pb & 63;            // 0..63 (64-f group)
        int lane = t & 63;
        int wv = t >> 6;              // 0..3 -> 16-f subgroup
        int fl = lane & 15;
        int kq = lane >> 4;           // 0..3
        int f = fbx * 64 + wv * 16 + fl;
        int fr = (f < NF) ? f : (NF - 1);

        float nf = 0.f, dr = 0.f, d1 = 0.f, d2 = 0.f, qr = 0.f, q1 = 0.f, q2 = 0.f;
        for (int i = 0; i < 25; i++) {
            int k = kq * 25 + i;
            float vr = frel[fr * EDIM + k];
            float v1 = fa1[fr * EDIM + k];
            float v2 = fa2[fr * EDIM + k];
            float rb = rel[b * EDIM + k];
            float a1 = arg1[b * EDIM + k];
            float a2 = arg2[b * EDIM + k];
            nf += vr * vr + v1 * v1 + v2 * v2;
            dr = fmaf(rb, vr, dr);
            d1 = fmaf(a1, v1, d1);
            d2 = fmaf(a2, v2, d2);
            qr = fmaf(rb, rb, qr);
            q1 = fmaf(a1, a1, q1);
            q2 = fmaf(a2, a2, q2);
        }
        nf += __shfl_xor(nf, 16); nf += __shfl_xor(nf, 32);
        dr += __shfl_xor(dr, 16); dr += __shfl_xor(dr, 32);
        d1 += __shfl_xor(d1, 16); d1 += __shfl_xor(d1, 32);
        d2 += __shfl_xor(d2, 16); d2 += __shfl_xor(d2, 32);
        qr += __shfl_xor(qr, 16); qr += __shfl_xor(qr, 32);
        q1 += __shfl_xor(q1, 16); q1 += __shfl_xor(q1, 32);
        q2 += __shfl_xor(q2, 16); q2 += __shfl_xor(q2, 32);
        if (kq == 0) {
            float psp = nf + qr + q1 - 2.f * (dr + d1);
            float ppo = nf + qr + q2 - 2.f * (dr + d2);
            if (f >= NF) { psp = __builtin_inff(); ppo = __builtin_inff(); }
            g_P[(0 * NB + b) * NP + f] = psp;
            g_P[(1 * NB + b) * NP + f] = ppo;
        }
    } else {
        int n = (bx - CONVB - PREPB) * 256 + t;
        if (n < NN) {
            const float4* ep = (const float4*)(ent + n * EDIM);
            float s = 0.f;
            #pragma unroll
            for (int i = 0; i < EDIM / 4; i++) {
                float4 v = ep[i];
                s += v.x * v.x + v.y * v.y + v.z * v.z + v.w * v.w;
            }
            g_e2[n] = s;
        }
    }
}

// Main: 128n x 64f tile, K=128 in one shot, looped over FPB=4 f-blocks with the
// running min carried in registers. P tile staged to LDS (broadcast reads).
__global__ void __launch_bounds__(256, 2) main_kernel() {
    __shared__ float4 smem4[4352];          // 69632 B (staging, reused as tr)
    __shared__ float4 sP4[256];             // 4 KB: P tile [g][b][16 chunks]
    float4* lA4  = smem4;                   // 32 KB: A 128 rows x 16 chunks
    float4* lB14 = smem4 + 2048;            // 16 KB
    float4* lB24 = smem4 + 3072;            // 16 KB
    float*  tr   = (float*)smem4;           // reuse: [2][128][TRS] = 69632 B

    const int t = threadIdx.x;
    const int n0 = blockIdx.x * BN;
    const int lane = t & 63;
    const int c = lane & 15;
    const int q = lane >> 4;
    const int w = t >> 6;
    const int w32 = w * 32;
    const int g2 = t >> 7;                  // uniform per wave
    const int row = t & 127;

    float m[NB];
    #pragma unroll
    for (int b = 0; b < NB; b++) m[b] = __builtin_inff();

    const float4* gA4  = (const float4*)g_A;
    const float4* gB14 = (const float4*)g_B1;
    const float4* gB24 = (const float4*)g_B2;

    #pragma unroll 1
    for (int ib = 0; ib < FPB; ib++) {
        const int fblk = blockIdx.y * FPB + ib;
        const int f0 = fblk * BF;

        // ---- stage: contiguous global float4 -> LDS with XOR chunk swizzle ----
        #pragma unroll
        for (int i = 0; i < 8; i++) {
            int gc = i * 256 + t;
            int rw = gc >> 4, ch = gc & 15;
            lA4[rw * 16 + (ch ^ (rw & 15))] = gA4[n0 * 16 + gc];
        }
        #pragma unroll
        for (int i = 0; i < 4; i++) {
            int gc = i * 256 + t;
            int rw = gc >> 4, ch = gc & 15;
            int sl = rw * 16 + (ch ^ (rw & 15));
            lB14[sl] = gB14[f0 * 16 + gc];
            lB24[sl] = gB24[f0 * 16 + gc];
        }
        {   // P tile: thread -> (g = t>>7, b = (t>>4)&7, chunk = t&15)
            int pg = t >> 7, pb = (t >> 4) & 7, q4 = t & 15;
            sP4[t] = ((const float4*)(g_P + (pg * NB + pb) * NP + f0))[q4];
        }
        __syncthreads();

        // ---- MFMA phase ----
        const short8* pA  = (const short8*)lA4;
        const short8* pB1 = (const short8*)lB14;
        const short8* pB2 = (const short8*)lB24;

        floatx4 acc[2][2][4];                   // [g][mt][ft]
        #pragma unroll
        for (int g = 0; g < 2; g++)
            #pragma unroll
            for (int mt = 0; mt < 2; mt++)
                #pragma unroll
                for (int ft = 0; ft < 4; ft++)
                    acc[g][mt][ft] = (floatx4){0.f, 0.f, 0.f, 0.f};

        #pragma unroll
        for (int s = 0; s < 4; s++) {           // K-steps of 32
            const int base = s * 4 + q;
            short8 a0 = pA[(w32 + c) * 16 + (base ^ c)];
            short8 a1 = pA[(w32 + 16 + c) * 16 + (base ^ c)];
            #pragma unroll
            for (int ft = 0; ft < 4; ft++) {
                int sl = (ft * 16 + c) * 16 + (base ^ c);
                short8 b1 = pB1[sl];
                short8 b2 = pB2[sl];
                acc[0][0][ft] = __builtin_amdgcn_mfma_f32_16x16x32_bf16(a0, b2, acc[0][0][ft], 0, 0, 0);
                acc[0][1][ft] = __builtin_amdgcn_mfma_f32_16x16x32_bf16(a1, b2, acc[0][1][ft], 0, 0, 0);
                acc[1][0][ft] = __builtin_amdgcn_mfma_f32_16x16x32_bf16(a0, b1, acc[1][0][ft], 0, 0, 0);
                acc[1][1][ft] = __builtin_amdgcn_mfma_f32_16x16x32_bf16(a1, b1, acc[1][1][ft], 0, 0, 0);
            }
        }

        __syncthreads();   // all frag reads done; staging LDS now reusable

        // ---- transpose G -> tr[g][row][f].  C layout: col(f)=c, row(n)=q*4+r.
        #pragma unroll
        for (int g = 0; g < 2; g++)
            #pragma unroll
            for (int mt = 0; mt < 2; mt++)
                #pragma unroll
                for (int ft = 0; ft < 4; ft++)
                    #pragma unroll
                    for (int r = 0; r < 4; r++)
                        tr[(g * BN + w32 + mt * 16 + q * 4 + r) * TRS + ft * 16 + c] =
                            acc[g][mt][ft][r];
        __syncthreads();

        // ---- phase 2: thread owns (g,row); fold 64 f's; P from LDS broadcast ----
        const float4* trg = (const float4*)(tr + (g2 * BN + row) * TRS);
        float4 G4[16];
        #pragma unroll
        for (int ch = 0; ch < 16; ch++) G4[ch] = trg[ch];

        #pragma unroll
        for (int b = 0; b < NB; b++) {
            const float4* Pl = (const float4*)sP4 + (g2 * NB + b) * 16;  // wave-uniform
            float4 m4 = {__builtin_inff(), __builtin_inff(), __builtin_inff(), __builtin_inff()};
            #pragma unroll
            for (int ch = 0; ch < 16; ch += 2) {
                float4 pa = Pl[ch];
                float4 pb = Pl[ch + 1];
                float ax = fmaf(-2.f, G4[ch].x, pa.x), bx = fmaf(-2.f, G4[ch + 1].x, pb.x);
                float ay = fmaf(-2.f, G4[ch].y, pa.y), by = fmaf(-2.f, G4[ch + 1].y, pb.y);
                float az = fmaf(-2.f, G4[ch].z, pa.z), bz = fmaf(-2.f, G4[ch + 1].z, pb.z);
                float aw = fmaf(-2.f, G4[ch].w, pa.w), bw = fmaf(-2.f, G4[ch + 1].w, pb.w);
                m4.x = fminf(m4.x, fminf(ax, bx));   // -> v_min3_f32
                m4.y = fminf(m4.y, fminf(ay, by));
                m4.z = fminf(m4.z, fminf(az, bz));
                m4.w = fminf(m4.w, fminf(aw, bw));
            }
            float mm = fminf(fminf(m4.x, m4.y), fminf(m4.z, m4.w));
            m[b] = fminf(m[b], mm);
        }
        __syncthreads();   // protect tr/sP4 before next iteration's staging
    }

    #pragma unroll
    for (int b = 0; b < NB; b++)
        g_part[((g2 * NB + b) * NYB + blockIdx.y) * NP + n0 + row] = m[b];
}

__global__ void finalize(float* __restrict__ out) {
    int idx = blockIdx.x * 256 + threadIdx.x;   // over 2*NB*NN, out layout (g*NB+b)*NN+n
    if (idx >= 2 * NB * NN) return;
    int sb = idx / NN;
    int n = idx % NN;
    float m = __builtin_inff();
    #pragma unroll
    for (int j = 0; j < NYB; j += 2) {
        float a = g_part[(sb * NYB + j) * NP + n];
        float b = g_part[(sb * NYB + j + 1) * NP + n];
        m = fminf(m, fminf(a, b));              // -> v_min3_f32
    }
    float d2 = fmaxf(m + g_e2[n], 0.f);
    out[idx] = expf(-0.5f * d2);
}

extern "C" void kernel_launch(void* const* d_in, const int* in_sizes, int n_in,
                              void* d_out, int out_size, void* d_ws, size_t ws_size,
                              hipStream_t stream) {
    const float* rel  = (const float*)d_in[0];
    const float* arg1 = (const float*)d_in[1];
    const float* arg2 = (const float*)d_in[2];
    const float* frel = (const float*)d_in[3];
    const float* fa1  = (const float*)d_in[4];
    const float* fa2  = (const float*)d_in[5];
    const float* ent  = (const float*)d_in[6];
    float* out = (float*)d_out;

    prep<<<dim3(CONVB + PREPB + E2B), 256, 0, stream>>>(rel, arg1, arg2, frel, fa1, fa2, ent);
    main_kernel<<<dim3(NP / BN, NYB), 256, 0, stream>>>();
    finalize<<<(2 * NB * NN + 255) / 256, 256, 0, stream>>>(out);
}

// Round 2
// 127.384 us; speedup vs baseline: 1.0710x; 1.0443x over previous
//
#include <hip/hip_runtime.h>
#include <math.h>

#define EDIM 100
#define KP   128          // padded K
#define NF   4000
#define NN   4000
#define NB   8
#define NP   4096         // padded N and F
#define BN   128          // n-rows per block
#define BF   64           // f-cols per block
#define FPB  4            // f-blocks folded per main block
#define NYB  16           // gridDim.y of main (64 f-blocks / FPB)

#define CONVB (3 * NP * 16 / 256)     // 768 convert blocks (short8 per thread)
#define PREPB ((NP / 64) * NB)        // 512 precompute_P blocks
#define E2B   ((NN + 255) / 256)      // 16 e2 blocks

typedef __attribute__((ext_vector_type(8))) short short8;
typedef __attribute__((ext_vector_type(4))) float floatx4;

// Static device scratch.
__device__ __align__(16) unsigned short g_A [NP * KP];   // ent  bf16, K-padded
__device__ __align__(16) unsigned short g_B1[NP * KP];   // fa1  bf16
__device__ __align__(16) unsigned short g_B2[NP * KP];   // fa2  bf16
__device__ __align__(16) float g_P[2 * NB * NP];         // [g][b][f], +INF on f-pad
__device__ float g_e2[NN];
__device__ float g_part[2 * NB * NYB * NP];              // [g][b][yblk][n]  (4 MB)

__device__ __forceinline__ unsigned short f2bf(float x) {
    union { float f; unsigned int u; } v; v.f = x;
    unsigned int r = v.u + 0x7FFFu + ((v.u >> 16) & 1u);  // RNE
    return (unsigned short)(r >> 16);
}

// 16-lane (DPP row) min reduction, pure VALU: after 4 steps every lane in the
// row of 16 holds min over the row.  row_mirror, row_half_mirror, quad reverse,
// quad pair-swap together cover all 16 lanes.
__device__ __forceinline__ float row16_min(float x) {
    int i;
    i = __builtin_amdgcn_mov_dpp(__float_as_int(x), 0x140, 0xF, 0xF, false); // row_mirror
    x = fminf(x, __int_as_float(i));
    i = __builtin_amdgcn_mov_dpp(__float_as_int(x), 0x141, 0xF, 0xF, false); // row_half_mirror
    x = fminf(x, __int_as_float(i));
    i = __builtin_amdgcn_mov_dpp(__float_as_int(x), 0x1B, 0xF, 0xF, false);  // quad reverse
    x = fminf(x, __int_as_float(i));
    i = __builtin_amdgcn_mov_dpp(__float_as_int(x), 0xB1, 0xF, 0xF, false);  // quad swap pairs
    x = fminf(x, __int_as_float(i));
    return x;
}

// ---- merged prep: convert (768 blk) | precompute_P (512 blk) | e2 (16 blk) ----
__global__ void prep(const float* __restrict__ rel,  const float* __restrict__ arg1,
                     const float* __restrict__ arg2, const float* __restrict__ frel,
                     const float* __restrict__ fa1,  const float* __restrict__ fa2,
                     const float* __restrict__ ent) {
    const int bx = blockIdx.x;
    const int t  = threadIdx.x;

    if (bx < CONVB) {
        // fp32 [4000][100] -> bf16 [4096][128], one short8 (8 cols) per thread
        int plane = bx >> 8;                    // 256 blocks per plane
        int local = ((bx & 255) << 8) | t;      // 0 .. NP*16-1
        int row = local >> 4, j = local & 15;   // j = 8-col chunk
        const float* src = (plane == 0) ? ent : (plane == 1) ? fa1 : fa2;
        unsigned short* dst = (plane == 0) ? g_A : (plane == 1) ? g_B1 : g_B2;
        short8 o = (short8){0, 0, 0, 0, 0, 0, 0, 0};
        if (row < NF && j <= 12) {
            if (j < 12) {
                float4 v0 = *(const float4*)(src + row * EDIM + j * 8);
                float4 v1 = *(const float4*)(src + row * EDIM + j * 8 + 4);
                o[0] = (short)f2bf(v0.x); o[1] = (short)f2bf(v0.y);
                o[2] = (short)f2bf(v0.z); o[3] = (short)f2bf(v0.w);
                o[4] = (short)f2bf(v1.x); o[5] = (short)f2bf(v1.y);
                o[6] = (short)f2bf(v1.z); o[7] = (short)f2bf(v1.w);
            } else {  // j == 12: cols 96..99 valid, 100..103 zero
                float4 v0 = *(const float4*)(src + row * EDIM + 96);
                o[0] = (short)f2bf(v0.x); o[1] = (short)f2bf(v0.y);
                o[2] = (short)f2bf(v0.z); o[3] = (short)f2bf(v0.w);
            }
        }
        *(short8*)(dst + row * KP + j * 8) = o;
    } else if (bx < CONVB + PREPB) {
        // P[g][b][f]; one wave per 16 f's, lanes = (f_local 16) x (k-quarter 4)
        int pb = bx - CONVB;
        int b   = pb >> 6;            // 0..7
        int fbx = pb & 63;            // 0..63 (64-f group)
        int lane = t & 63;
        int wv = t >> 6;              // 0..3 -> 16-f subgroup
        int fl = lane & 15;
        int kq = lane >> 4;           // 0..3
        int f = fbx * 64 + wv * 16 + fl;
        int fr = (f < NF) ? f : (NF - 1);

        float nf = 0.f, dr = 0.f, d1 = 0.f, d2 = 0.f, qr = 0.f, q1 = 0.f, q2 = 0.f;
        for (int i = 0; i < 25; i++) {
            int k = kq * 25 + i;
            float vr = frel[fr * EDIM + k];
            float v1 = fa1[fr * EDIM + k];
            float v2 = fa2[fr * EDIM + k];
            float rb = rel[b * EDIM + k];
            float a1 = arg1[b * EDIM + k];
            float a2 = arg2[b * EDIM + k];
            nf += vr * vr + v1 * v1 + v2 * v2;
            dr = fmaf(rb, vr, dr);
            d1 = fmaf(a1, v1, d1);
            d2 = fmaf(a2, v2, d2);
            qr = fmaf(rb, rb, qr);
            q1 = fmaf(a1, a1, q1);
            q2 = fmaf(a2, a2, q2);
        }
        nf += __shfl_xor(nf, 16); nf += __shfl_xor(nf, 32);
        dr += __shfl_xor(dr, 16); dr += __shfl_xor(dr, 32);
        d1 += __shfl_xor(d1, 16); d1 += __shfl_xor(d1, 32);
        d2 += __shfl_xor(d2, 16); d2 += __shfl_xor(d2, 32);
        qr += __shfl_xor(qr, 16); qr += __shfl_xor(qr, 32);
        q1 += __shfl_xor(q1, 16); q1 += __shfl_xor(q1, 32);
        q2 += __shfl_xor(q2, 16); q2 += __shfl_xor(q2, 32);
        if (kq == 0) {
            float psp = nf + qr + q1 - 2.f * (dr + d1);
            float ppo = nf + qr + q2 - 2.f * (dr + d2);
            if (f >= NF) { psp = __builtin_inff(); ppo = __builtin_inff(); }
            g_P[(0 * NB + b) * NP + f] = psp;
            g_P[(1 * NB + b) * NP + f] = ppo;
        }
    } else {
        int n = (bx - CONVB - PREPB) * 256 + t;
        if (n < NN) {
            const float4* ep = (const float4*)(ent + n * EDIM);
            float s = 0.f;
            #pragma unroll
            for (int i = 0; i < EDIM / 4; i++) {
                float4 v = ep[i];
                s += v.x * v.x + v.y * v.y + v.z * v.z + v.w * v.w;
            }
            g_e2[n] = s;
        }
    }
}

// Main: 128n x 64f tile, K=128 in one shot, FPB=4 f-blocks per block.
// P folded directly in MFMA accumulator layout (f = ft*16 + c); running min
// per thread in registers; 16-lane c-reduction ONCE at the end via DPP.
// No transpose phase, no G round-trip through LDS, 2 barriers/iter.
__global__ void __launch_bounds__(256, 2) main_kernel() {
    __shared__ float4 smem4[4352];          // 69632 B
    float4* lA4  = smem4;                   // 32 KB: A 128 rows x 16 chunks (staged once)
    float4* lB14 = smem4 + 2048;            // 16 KB
    float4* lB24 = smem4 + 3072;            // 16 KB
    float*  sPf  = (float*)(smem4 + 4096);  // 4 KB: P tile [2][8][64]

    const int t = threadIdx.x;
    const int n0 = blockIdx.x * BN;
    const int by = blockIdx.y;
    const int lane = t & 63;
    const int c = lane & 15;
    const int q = lane >> 4;
    const int w = t >> 6;
    const int w32 = w * 32;

    floatx4 m2[2][8][2];                    // [g][b][mt] running min over f (per r lane-row)
    #pragma unroll
    for (int g = 0; g < 2; g++)
        #pragma unroll
        for (int b = 0; b < NB; b++)
            #pragma unroll
            for (int mt = 0; mt < 2; mt++)
                m2[g][b][mt] = (floatx4){__builtin_inff(), __builtin_inff(),
                                         __builtin_inff(), __builtin_inff()};

    const float4* gA4  = (const float4*)g_A;
    const float4* gB14 = (const float4*)g_B1;
    const float4* gB24 = (const float4*)g_B2;

    // ---- stage A once (n-tile invariant across f-blocks) ----
    #pragma unroll
    for (int i = 0; i < 8; i++) {
        int gc = i * 256 + t;
        int rw = gc >> 4, ch = gc & 15;
        lA4[rw * 16 + (ch ^ (rw & 15))] = gA4[n0 * 16 + gc];
    }

    #pragma unroll 1
    for (int ib = 0; ib < FPB; ib++) {
        const int f0 = (by * FPB + ib) * BF;

        // ---- stage B1/B2 + P ----
        #pragma unroll
        for (int i = 0; i < 4; i++) {
            int gc = i * 256 + t;
            int rw = gc >> 4, ch = gc & 15;
            int sl = rw * 16 + (ch ^ (rw & 15));
            lB14[sl] = gB14[f0 * 16 + gc];
            lB24[sl] = gB24[f0 * 16 + gc];
        }
        {
            int pg = t >> 7, pb = (t >> 4) & 7, q4 = t & 15;
            ((float4*)sPf)[t] = ((const float4*)(g_P + (pg * NB + pb) * NP + f0))[q4];
        }
        __syncthreads();

        const short8* pA  = (const short8*)lA4;
        const short8* pB1 = (const short8*)lB14;
        const short8* pB2 = (const short8*)lB24;

        // g=0 pairs with B2 (sp: entity . fact_arg2), g=1 with B1 (po)
        #pragma unroll
        for (int g = 0; g < 2; g++) {
            const short8* pB = g ? pB1 : pB2;
            floatx4 acc[2][4];              // [mt][ft]
            #pragma unroll
            for (int mt = 0; mt < 2; mt++)
                #pragma unroll
                for (int ft = 0; ft < 4; ft++)
                    acc[mt][ft] = (floatx4){0.f, 0.f, 0.f, 0.f};

            #pragma unroll
            for (int s = 0; s < 4; s++) {   // K-steps of 32
                const int base = s * 4 + q;
                short8 a0 = pA[(w32 + c) * 16 + (base ^ c)];
                short8 a1 = pA[(w32 + 16 + c) * 16 + (base ^ c)];
                #pragma unroll
                for (int ft = 0; ft < 4; ft++) {
                    short8 bb = pB[(ft * 16 + c) * 16 + (base ^ c)];
                    acc[0][ft] = __builtin_amdgcn_mfma_f32_16x16x32_bf16(a0, bb, acc[0][ft], 0, 0, 0);
                    acc[1][ft] = __builtin_amdgcn_mfma_f32_16x16x32_bf16(a1, bb, acc[1][ft], 0, 0, 0);
                }
            }

            // ---- fold P in accumulator layout: f = ft*16 + c ----
            #pragma unroll
            for (int b = 0; b < NB; b++) {
                const float* Pb = sPf + (g * NB + b) * 64;
                float p0 = Pb[c];           // broadcast-group LDS reads (ds_read2-mergeable)
                float p1 = Pb[16 + c];
                float p2 = Pb[32 + c];
                float p3 = Pb[48 + c];
                #pragma unroll
                for (int mt = 0; mt < 2; mt++) {
                    #pragma unroll
                    for (int r = 0; r < 4; r++) {
                        float t0 = fmaf(-2.f, acc[mt][0][r], p0);
                        float t1 = fmaf(-2.f, acc[mt][1][r], p1);
                        float t2 = fmaf(-2.f, acc[mt][2][r], p2);
                        float t3 = fmaf(-2.f, acc[mt][3][r], p3);
                        float u = fminf(fminf(t0, t1), t2);             // v_min3
                        m2[g][b][mt][r] = fminf(fminf(u, t3), m2[g][b][mt][r]);  // v_min3
                    }
                }
            }
        }
        if (ib < FPB - 1) __syncthreads();  // before next stage overwrites B/P
    }

    // ---- once: reduce over the 16 c-lanes (DPP, pure VALU) ----
    #pragma unroll
    for (int g = 0; g < 2; g++)
        #pragma unroll
        for (int b = 0; b < NB; b++)
            #pragma unroll
            for (int mt = 0; mt < 2; mt++)
                #pragma unroll
                for (int r = 0; r < 4; r++)
                    m2[g][b][mt][r] = row16_min(m2[g][b][mt][r]);

    // lane c==0 of each q-group writes float4 (4 contiguous rows)
    if (c == 0) {
        #pragma unroll
        for (int g = 0; g < 2; g++)
            #pragma unroll
            for (int b = 0; b < NB; b++)
                #pragma unroll
                for (int mt = 0; mt < 2; mt++)
                    *(float4*)&g_part[((g * NB + b) * NYB + by) * NP +
                                      n0 + w32 + mt * 16 + q * 4] =
                        (float4){m2[g][b][mt][0], m2[g][b][mt][1],
                                 m2[g][b][mt][2], m2[g][b][mt][3]};
    }
}

__global__ void finalize(float* __restrict__ out) {
    int idx = blockIdx.x * 256 + threadIdx.x;   // over 2*NB*NN, out layout (g*NB+b)*NN+n
    if (idx >= 2 * NB * NN) return;
    int sb = idx / NN;
    int n = idx % NN;
    float m = __builtin_inff();
    #pragma unroll
    for (int j = 0; j < NYB; j += 2) {
        float a = g_part[(sb * NYB + j) * NP + n];
        float b = g_part[(sb * NYB + j + 1) * NP + n];
        m = fminf(m, fminf(a, b));              // v_min3
    }
    float d2 = fmaxf(m + g_e2[n], 0.f);
    out[idx] = expf(-0.5f * d2);
}

extern "C" void kernel_launch(void* const* d_in, const int* in_sizes, int n_in,
                              void* d_out, int out_size, void* d_ws, size_t ws_size,
                              hipStream_t stream) {
    const float* rel  = (const float*)d_in[0];
    const float* arg1 = (const float*)d_in[1];
    const float* arg2 = (const float*)d_in[2];
    const float* frel = (const float*)d_in[3];
    const float* fa1  = (const float*)d_in[4];
    const float* fa2  = (const float*)d_in[5];
    const float* ent  = (const float*)d_in[6];
    float* out = (float*)d_out;

    prep<<<dim3(CONVB + PREPB + E2B), 256, 0, stream>>>(rel, arg1, arg2, frel, fa1, fa2, ent);
    main_kernel<<<dim3(NP / BN, NYB), 256, 0, stream>>>();
    finalize<<<(2 * NB * NN + 255) / 256, 256, 0, stream>>>(out);
}

// Round 4
// 112.517 us; speedup vs baseline: 1.2125x; 1.1321x over previous
//
#include <hip/hip_runtime.h>
#include <math.h>

#define EDIM 100
#define KP   128          // padded K
#define NF   4000
#define NN   4000
#define NB   8
#define NP   4096         // padded N and F
#define BN   128          // n-rows per block
#define BF   64           // f per f-block
#define FPB  4            // f-blocks folded per main block
#define NYB  16           // 64 f-blocks / FPB

#define CONVB (3 * NP * 16 / 256)     // 768 convert blocks (short8 per thread)
#define PREPB ((NP / 64) * NB)        // 512 precompute_P blocks (256 thr, 64f x 1b)
#define E2B   ((NN + 255) / 256)      // 16 e2 blocks

typedef __attribute__((ext_vector_type(8))) short short8;
typedef __attribute__((ext_vector_type(4))) float floatx4;

typedef const __attribute__((address_space(1))) unsigned int* gas_u32;
typedef __attribute__((address_space(3))) unsigned int* las_u32;

// Static device scratch.
__device__ __align__(16) unsigned short g_A [NP * KP];   // ent  bf16, K-padded
__device__ __align__(16) unsigned short g_B1[NP * KP];   // fa1  bf16
__device__ __align__(16) unsigned short g_B2[NP * KP];   // fa2  bf16
// P in main-ready layout: [g][fblk 64][chunk 128][ft 4] floats.
// chunk = c*8 + (b ^ (c&7))  (bank-swizzled so the fold's b128 reads are 2-way max)
__device__ __align__(16) float g_P2[2 * 64 * 512];
__device__ float g_e2[NN];
__device__ float g_part[2 * NB * NYB * NP];              // [g][b][yblk][n]  (4 MB)

__device__ __forceinline__ unsigned short f2bf(float x) {
    union { float f; unsigned int u; } v; v.f = x;
    unsigned int r = v.u + 0x7FFFu + ((v.u >> 16) & 1u);  // RNE
    return (unsigned short)(r >> 16);
}

// 16-lane min reduction via DPP mirrors: XOR-masks {15,7,3,1} span all 16 lanes.
__device__ __forceinline__ float row16_min(float x) {
    int i;
    i = __builtin_amdgcn_mov_dpp(__float_as_int(x), 0x140, 0xF, 0xF, false); // row_mirror (^15)
    x = fminf(x, __int_as_float(i));
    i = __builtin_amdgcn_mov_dpp(__float_as_int(x), 0x141, 0xF, 0xF, false); // row_half_mirror (^7)
    x = fminf(x, __int_as_float(i));
    i = __builtin_amdgcn_mov_dpp(__float_as_int(x), 0x1B, 0xF, 0xF, false);  // quad reverse (^3)
    x = fminf(x, __int_as_float(i));
    i = __builtin_amdgcn_mov_dpp(__float_as_int(x), 0xB1, 0xF, 0xF, false);  // quad swap (^1)
    x = fminf(x, __int_as_float(i));
    return x;
}

// ---- merged prep: convert (768 blk) | precompute_P (512 blk) | e2 (16 blk) ----
__global__ void prep(const float* __restrict__ rel,  const float* __restrict__ arg1,
                     const float* __restrict__ arg2, const float* __restrict__ frel,
                     const float* __restrict__ fa1,  const float* __restrict__ fa2,
                     const float* __restrict__ ent) {
    const int bx = blockIdx.x;
    const int t  = threadIdx.x;

    if (bx < CONVB) {
        // fp32 [4000][100] -> bf16 [4096][128], one short8 (8 cols) per thread
        int plane = bx >> 8;                    // 256 blocks per plane
        int local = ((bx & 255) << 8) | t;      // 0 .. NP*16-1
        int row = local >> 4, j = local & 15;   // j = 8-col chunk
        const float* src = (plane == 0) ? ent : (plane == 1) ? fa1 : fa2;
        unsigned short* dst = (plane == 0) ? g_A : (plane == 1) ? g_B1 : g_B2;
        short8 o = (short8){0, 0, 0, 0, 0, 0, 0, 0};
        if (row < NF && j <= 12) {
            if (j < 12) {
                float4 v0 = *(const float4*)(src + row * EDIM + j * 8);
                float4 v1 = *(const float4*)(src + row * EDIM + j * 8 + 4);
                o[0] = (short)f2bf(v0.x); o[1] = (short)f2bf(v0.y);
                o[2] = (short)f2bf(v0.z); o[3] = (short)f2bf(v0.w);
                o[4] = (short)f2bf(v1.x); o[5] = (short)f2bf(v1.y);
                o[6] = (short)f2bf(v1.z); o[7] = (short)f2bf(v1.w);
            } else {  // j == 12: cols 96..99 valid, 100..103 zero
                float4 v0 = *(const float4*)(src + row * EDIM + 96);
                o[0] = (short)f2bf(v0.x); o[1] = (short)f2bf(v0.y);
                o[2] = (short)f2bf(v0.z); o[3] = (short)f2bf(v0.w);
            }
        }
        *(short8*)(dst + row * KP + j * 8) = o;
    } else if (bx < CONVB + PREPB) {
        // P for one (64-f group, b); 4 waves x 16 f; lanes = (fl 16) x (kq 4)
        int pb = bx - CONVB;
        int b   = pb >> 6;            // 0..7
        int fbx = pb & 63;            // 0..63 (64-f group)
        int lane = t & 63;
        int wv = t >> 6;              // 0..3 -> 16-f subgroup
        int fl = lane & 15;
        int kq = lane >> 4;           // 0..3
        int f = fbx * 64 + wv * 16 + fl;
        int fr = (f < NF) ? f : (NF - 1);

        float nf = 0.f, dr = 0.f, d1 = 0.f, d2 = 0.f, qr = 0.f, q1 = 0.f, q2 = 0.f;
        for (int i = 0; i < 25; i++) {
            int k = kq * 25 + i;
            float vr = frel[fr * EDIM + k];
            float v1 = fa1[fr * EDIM + k];
            float v2 = fa2[fr * EDIM + k];
            float rb = rel[b * EDIM + k];
            float a1 = arg1[b * EDIM + k];
            float a2 = arg2[b * EDIM + k];
            nf += vr * vr + v1 * v1 + v2 * v2;
            dr = fmaf(rb, vr, dr);
            d1 = fmaf(a1, v1, d1);
            d2 = fmaf(a2, v2, d2);
            qr = fmaf(rb, rb, qr);
            q1 = fmaf(a1, a1, q1);
            q2 = fmaf(a2, a2, q2);
        }
        nf += __shfl_xor(nf, 16); nf += __shfl_xor(nf, 32);
        dr += __shfl_xor(dr, 16); dr += __shfl_xor(dr, 32);
        d1 += __shfl_xor(d1, 16); d1 += __shfl_xor(d1, 32);
        d2 += __shfl_xor(d2, 16); d2 += __shfl_xor(d2, 32);
        qr += __shfl_xor(qr, 16); qr += __shfl_xor(qr, 32);
        q1 += __shfl_xor(q1, 16); q1 += __shfl_xor(q1, 32);
        q2 += __shfl_xor(q2, 16); q2 += __shfl_xor(q2, 32);
        if (kq == 0) {
            float psp = nf + qr + q1 - 2.f * (dr + d1);
            float ppo = nf + qr + q2 - 2.f * (dr + d2);
            if (f >= NF) { psp = __builtin_inff(); ppo = __builtin_inff(); }
            int fblk = f >> 6;
            int cc = f & 15;
            int ft = (f & 63) >> 4;
            int chunk = cc * 8 + (b ^ (cc & 7));
            g_P2[(0 * 64 + fblk) * 512 + chunk * 4 + ft] = psp;
            g_P2[(1 * 64 + fblk) * 512 + chunk * 4 + ft] = ppo;
        }
    } else {
        int n = (bx - CONVB - PREPB) * 256 + t;
        if (n < NN) {
            const float4* ep = (const float4*)(ent + n * EDIM);
            float s = 0.f;
            #pragma unroll
            for (int i = 0; i < EDIM / 4; i++) {
                float4 v = ep[i];
                s += v.x * v.x + v.y * v.y + v.z * v.z + v.w * v.w;
            }
            g_e2[n] = s;
        }
    }
}

// Main: grid (32, 16, 2); z = g.  Per block: 128 n-rows, FPB=4 f-blocks of 64.
// A fragments hoisted in registers (direct global loads, no LDS).
// B + P double-buffered in LDS via global_load_lds (pre-swizzled source).
// P folded in MFMA acc layout; running min in 64 VGPRs; DPP c-reduce at end.
__global__ void __launch_bounds__(256, 2) main_kernel() {
    __shared__ __align__(16) unsigned short sB[2][BF * 128]; // 2 x 16 KB, chunk-swizzled
    __shared__ __align__(16) float sP[2][512];               // 2 x 2 KB

    const int t = threadIdx.x;
    const int n0 = blockIdx.x * BN;
    const int by = blockIdx.y;
    const int g  = blockIdx.z;
    const int lane = t & 63;
    const int c = lane & 15;
    const int q = lane >> 4;
    const int w = t >> 6;
    const int w32 = w * 32;

    const unsigned short* gB = g ? g_B1 : g_B2;  // g=0(sp): entity . fa2; g=1(po): . fa1

    // ---- A fragments direct from global, hoisted across all f-blocks ----
    // lane pattern per (mt,s): 16 rows x 64B = 16 fully-consumed lines, L2-hot.
    short8 afrag[2][4];                          // [mt][s]  (32 VGPR)
    #pragma unroll
    for (int mt = 0; mt < 2; mt++)
        #pragma unroll
        for (int s = 0; s < 4; s++)
            afrag[mt][s] = *(const short8*)(g_A + (n0 + w32 + mt * 16 + c) * KP + (s * 4 + q) * 8);

    floatx4 m2[NB][2];                           // [b][mt] running min (64 VGPR)
    #pragma unroll
    for (int b = 0; b < NB; b++)
        #pragma unroll
        for (int mt = 0; mt < 2; mt++)
            m2[b][mt] = (floatx4){__builtin_inff(), __builtin_inff(),
                                  __builtin_inff(), __builtin_inff()};

    // DMA-stage B tile (16 KB) + P (2 KB) for f-block fb into buffer buf.
    // LDS dest is linear (wave base + lane*16); swizzle folded into global source.
    auto stage = [&](int buf, int fb) {
        const int f0r = fb * BF;
        #pragma unroll
        for (int j = 0; j < 4; j++) {
            int ck = (w * 4 + j) * 64 + lane;                 // dest chunk index
            int rw = ck >> 4, ch = ck & 15;
            int src = (f0r + rw) * 16 + (ch ^ (rw & 15));     // source chunk (pre-swizzle)
            __builtin_amdgcn_global_load_lds(
                (gas_u32)(gB + src * 8),
                (las_u32)(&sB[buf][(w * 4 + j) * 512]),
                16, 0, 0);
        }
        if (w < 2)
            __builtin_amdgcn_global_load_lds(
                (gas_u32)(g_P2 + (g * 64 + fb) * 512 + w * 256 + lane * 4),
                (las_u32)(&sP[buf][w * 256]),
                16, 0, 0);
    };

    stage(0, by * FPB);
    __syncthreads();   // vmcnt(0) drain: buffer 0 ready

    #pragma unroll 1
    for (int ib = 0; ib < FPB; ib++) {
        const int cur = ib & 1;
        if (ib + 1 < FPB) stage(cur ^ 1, by * FPB + ib + 1);  // async, drains at barrier

        const short8* pB = (const short8*)sB[cur];
        floatx4 acc[2][4];                       // [mt][ft]
        #pragma unroll
        for (int mt = 0; mt < 2; mt++)
            #pragma unroll
            for (int ft = 0; ft < 4; ft++)
                acc[mt][ft] = (floatx4){0.f, 0.f, 0.f, 0.f};

        #pragma unroll
        for (int s = 0; s < 4; s++) {            // K-steps of 32
            const int base = s * 4 + q;
            #pragma unroll
            for (int ft = 0; ft < 4; ft++) {
                short8 bb = pB[(ft * 16 + c) * 16 + (base ^ c)];
                acc[0][ft] = __builtin_amdgcn_mfma_f32_16x16x32_bf16(afrag[0][s], bb, acc[0][ft], 0, 0, 0);
                acc[1][ft] = __builtin_amdgcn_mfma_f32_16x16x32_bf16(afrag[1][s], bb, acc[1][ft], 0, 0, 0);
            }
        }

        // ---- fold P in acc layout: f = ft*16 + c; one b128 per b ----
        const float* Pf = sP[cur];
        #pragma unroll
        for (int b = 0; b < NB; b++) {
            floatx4 p = *(const floatx4*)(Pf + (c * 8 + (b ^ (c & 7))) * 4);
            #pragma unroll
            for (int mt = 0; mt < 2; mt++) {
                #pragma unroll
                for (int r = 0; r < 4; r++) {
                    float t0 = fmaf(-2.f, acc[mt][0][r], p[0]);
                    float t1 = fmaf(-2.f, acc[mt][1][r], p[1]);
                    float t2 = fmaf(-2.f, acc[mt][2][r], p[2]);
                    float t3 = fmaf(-2.f, acc[mt][3][r], p[3]);
                    float u = fminf(fminf(t0, t1), t2);                   // v_min3
                    m2[b][mt][r] = fminf(fminf(u, t3), m2[b][mt][r]);     // v_min3
                }
            }
        }
        if (ib + 1 < FPB) __syncthreads();       // next buffer staged + this one reusable
    }

    // ---- once: reduce over 16 c-lanes (DPP, pure VALU) ----
    #pragma unroll
    for (int b = 0; b < NB; b++)
        #pragma unroll
        for (int mt = 0; mt < 2; mt++)
            #pragma unroll
            for (int r = 0; r < 4; r++)
                m2[b][mt][r] = row16_min(m2[b][mt][r]);

    if (c == 0) {
        #pragma unroll
        for (int b = 0; b < NB; b++)
            #pragma unroll
            for (int mt = 0; mt < 2; mt++)
                *(float4*)&g_part[((g * NB + b) * NYB + by) * NP +
                                  n0 + w32 + mt * 16 + q * 4] =
                    (float4){m2[b][mt][0], m2[b][mt][1], m2[b][mt][2], m2[b][mt][3]};
    }
}

__global__ void finalize(float* __restrict__ out) {
    int idx = blockIdx.x * 256 + threadIdx.x;   // over 2*NB*NN, out layout (g*NB+b)*NN+n
    if (idx >= 2 * NB * NN) return;
    int sb = idx / NN;
    int n = idx % NN;
    float m = __builtin_inff();
    #pragma unroll
    for (int j = 0; j < NYB; j += 2) {
        float a = g_part[(sb * NYB + j) * NP + n];
        float b = g_part[(sb * NYB + j + 1) * NP + n];
        m = fminf(m, fminf(a, b));              // v_min3
    }
    float d2 = fmaxf(m + g_e2[n], 0.f);
    out[idx] = expf(-0.5f * d2);
}

extern "C" void kernel_launch(void* const* d_in, const int* in_sizes, int n_in,
                              void* d_out, int out_size, void* d_ws, size_t ws_size,
                              hipStream_t stream) {
    const float* rel  = (const float*)d_in[0];
    const float* arg1 = (const float*)d_in[1];
    const float* arg2 = (const float*)d_in[2];
    const float* frel = (const float*)d_in[3];
    const float* fa1  = (const float*)d_in[4];
    const float* fa2  = (const float*)d_in[5];
    const float* ent  = (const float*)d_in[6];
    float* out = (float*)d_out;

    prep<<<dim3(CONVB + PREPB + E2B), 256, 0, stream>>>(rel, arg1, arg2, frel, fa1, fa2, ent);
    main_kernel<<<dim3(NP / BN, NYB, 2), 256, 0, stream>>>();
    finalize<<<(2 * NB * NN + 255) / 256, 256, 0, stream>>>(out);
}